// Round 5
// baseline (342.427 us; speedup 1.0000x reference)
//
#include <hip/hip_runtime.h>
#include <hip/hip_bf16.h>
#include <math.h>

#define D 20
#define NROWS 4
#define TPB 256
#define NBLOCKS 1024   // 4 blocks/CU resident at <=128 VGPR -> 16 waves/CU

// Fused per-row pipeline, constants LDS-resident (filled once per block):
//   h2 = relu(x @ M + c)   with M = W^T R (DxD), c = 1 + b @ R
//   h3 = h2 @ W^T + b
//   accumulate S += sum(h3), Q += sum(h3^2)
// R3 lesson: LICM hoists loop-invariant LDS loads into ~440 VGPRs -> spill;
//   defeated with opaque per-iteration zero offset (asm "+v").
// R4 lesson: latency-starved (occ 9.9%, VALUBusy 31%) -> NR=4 + bounds(256,4)
//   for 4 waves/SIMD, grid=1024 so all blocks co-resident with ~2 iters/thread.
template <int NR>
__device__ __forceinline__ void process_rows(const float* __restrict__ xp,
                                             const float* sM, const float* sW,
                                             const float* sC, const float* sB,
                                             float& sacc, float& qacc) {
    float h2[NR][D];
    const float4* C4 = (const float4*)sC;
#pragma unroll
    for (int q = 0; q < D / 4; ++q) {
        float4 c = C4[q];
#pragma unroll
        for (int rr = 0; rr < NR; ++rr) {
            h2[rr][4 * q + 0] = c.x;
            h2[rr][4 * q + 1] = c.y;
            h2[rr][4 * q + 2] = c.z;
            h2[rr][4 * q + 3] = c.w;
        }
    }

    const float4* xp4 = (const float4*)xp;
    const float4* M4 = (const float4*)sM;
#pragma unroll
    for (int q = 0; q < D / 4; ++q) {
        float4 xv[NR];
#pragma unroll
        for (int rr = 0; rr < NR; ++rr) xv[rr] = xp4[rr * (D / 4) + q];
#pragma unroll
        for (int dd = 0; dd < 4; ++dd) {
            const int d = 4 * q + dd;
#pragma unroll
            for (int kq = 0; kq < D / 4; ++kq) {
                float4 m = M4[d * (D / 4) + kq];
#pragma unroll
                for (int rr = 0; rr < NR; ++rr) {
                    float xs = (dd == 0) ? xv[rr].x
                             : (dd == 1) ? xv[rr].y
                             : (dd == 2) ? xv[rr].z
                                         : xv[rr].w;
                    h2[rr][4 * kq + 0] = fmaf(xs, m.x, h2[rr][4 * kq + 0]);
                    h2[rr][4 * kq + 1] = fmaf(xs, m.y, h2[rr][4 * kq + 1]);
                    h2[rr][4 * kq + 2] = fmaf(xs, m.z, h2[rr][4 * kq + 2]);
                    h2[rr][4 * kq + 3] = fmaf(xs, m.w, h2[rr][4 * kq + 3]);
                }
            }
        }
    }

#pragma unroll
    for (int rr = 0; rr < NR; ++rr)
#pragma unroll
        for (int k = 0; k < D; ++k) h2[rr][k] = fmaxf(h2[rr][k], 0.f);

    const float4* W4 = (const float4*)sW;
#pragma unroll
    for (int j = 0; j < D; ++j) {
        float bj = sB[j];
        float h3[NR];
#pragma unroll
        for (int rr = 0; rr < NR; ++rr) h3[rr] = bj;
#pragma unroll
        for (int kq = 0; kq < D / 4; ++kq) {
            float4 w = W4[j * (D / 4) + kq];
#pragma unroll
            for (int rr = 0; rr < NR; ++rr) {
                h3[rr] = fmaf(h2[rr][4 * kq + 0], w.x, h3[rr]);
                h3[rr] = fmaf(h2[rr][4 * kq + 1], w.y, h3[rr]);
                h3[rr] = fmaf(h2[rr][4 * kq + 2], w.z, h3[rr]);
                h3[rr] = fmaf(h2[rr][4 * kq + 3], w.w, h3[rr]);
            }
        }
#pragma unroll
        for (int rr = 0; rr < NR; ++rr) {
            sacc += h3[rr];
            qacc = fmaf(h3[rr], h3[rr], qacc);
        }
    }
}

__global__ void __launch_bounds__(TPB, 4)
fancy_mlp_main(const float* __restrict__ x,
               const float* __restrict__ W,
               const float* __restrict__ bvec,
               const float* __restrict__ R,
               double* __restrict__ partS,
               double* __restrict__ partQ,
               long long nrows) {
    __shared__ __align__(16) float sM[D * D];   // M = W^T R
    __shared__ __align__(16) float sW[D * D];   // W copy
    __shared__ __align__(16) float sC[D];       // c = 1 + b @ R
    __shared__ __align__(16) float sB[D];       // b copy

    // Per-block constant build: identical fp ops in every block -> deterministic.
    for (int t = threadIdx.x; t < 2 * D * D + 2 * D; t += TPB) {
        if (t < D * D) {
            int d = t / D, k = t % D;
            float s = 0.f;
#pragma unroll
            for (int j = 0; j < D; ++j) s = fmaf(W[j * D + d], R[j * D + k], s);
            sM[t] = s;
        } else if (t < D * D + D) {
            int k = t - D * D;
            float s = 1.f;
#pragma unroll
            for (int j = 0; j < D; ++j) s = fmaf(bvec[j], R[j * D + k], s);
            sC[k] = s;
        } else if (t < 2 * D * D + D) {
            int u = t - (D * D + D);
            sW[u] = W[u];
        } else {
            sB[t - (2 * D * D + D)] = bvec[t - (2 * D * D + D)];
        }
    }
    __syncthreads();

    long long gtid = (long long)blockIdx.x * TPB + threadIdx.x;
    long long gstride = (long long)gridDim.x * TPB;
    long long ngroups = nrows / NROWS;

    // Per-thread float accumulators (<= ~200 terms each: fp32 exact enough),
    // promoted to double only at the cross-thread reduce.
    float sacc = 0.f, qacc = 0.f;
#pragma clang loop unroll(disable)
    for (long long g = gtid; g < ngroups; g += gstride) {
        // Opaque zero re-materialized every iteration: keeps the 440 LDS
        // constants loop-variant so LICM can't hoist them into VGPRs (R3 spill).
        int zoff = 0;
        asm volatile("" : "+v"(zoff));
        process_rows<NROWS>(x + g * (NROWS * D),
                            sM + zoff, sW + zoff, sC + zoff, sB + zoff,
                            sacc, qacc);
    }
    long long tr = ngroups * NROWS + gtid;   // nrows % NROWS == 0 here; safety
    if (tr < nrows) {
        process_rows<1>(x + tr * D, sM, sW, sC, sB, sacc, qacc);
    }

    double sd = (double)sacc, qd = (double)qacc;
    // wave(64) shuffle reduce, then per-block partial
#pragma unroll
    for (int off = 32; off > 0; off >>= 1) {
        sd += __shfl_down(sd, off);
        qd += __shfl_down(qd, off);
    }
    __shared__ double rS[TPB / 64], rQ[TPB / 64];
    int lane = threadIdx.x & 63;
    int wid = threadIdx.x >> 6;
    if (lane == 0) { rS[wid] = sd; rQ[wid] = qd; }
    __syncthreads();
    if (threadIdx.x == 0) {
        double S = 0.0, Q = 0.0;
#pragma unroll
        for (int w = 0; w < TPB / 64; ++w) { S += rS[w]; Q += rQ[w]; }
        partS[blockIdx.x] = S;
        partQ[blockIdx.x] = Q;
    }
}

__global__ void __launch_bounds__(256)
fancy_mlp_finish(const double* __restrict__ partS,
                 const double* __restrict__ partQ,
                 int nb, float* __restrict__ out) {
    double s = 0.0, q = 0.0;
    for (int i = threadIdx.x; i < nb; i += 256) { s += partS[i]; q += partQ[i]; }
#pragma unroll
    for (int off = 32; off > 0; off >>= 1) {
        s += __shfl_down(s, off);
        q += __shfl_down(q, off);
    }
    __shared__ double rS[4], rQ[4];
    int lane = threadIdx.x & 63;
    int wid = threadIdx.x >> 6;
    if (lane == 0) { rS[wid] = s; rQ[wid] = q; }
    __syncthreads();
    if (threadIdx.x == 0) {
        double S = rS[0] + rS[1] + rS[2] + rS[3];
        double Q = rQ[0] + rQ[1] + rQ[2] + rQ[3];
        float n = (float)sqrt(Q);
        // torch: while norm > 1: x /= 2  (halving exact in fp32)
        int k = 0;
        float nn = n;
        while (nn > 1.0f) { nn *= 0.5f; ++k; }
        float mult = (nn < 0.8f) ? 10.0f : 1.0f;
        double scale = ldexp(1.0, -k);
        out[0] = (float)(S * scale * (double)mult);
    }
}

extern "C" void kernel_launch(void* const* d_in, const int* in_sizes, int n_in,
                              void* d_out, int out_size, void* d_ws, size_t ws_size,
                              hipStream_t stream) {
    const float* x = (const float*)d_in[0];
    const float* W = (const float*)d_in[1];
    const float* b = (const float*)d_in[2];
    const float* R = (const float*)d_in[3];

    long long nrows = (long long)in_sizes[0] / D;      // 2,000,000
    long long maxb = (long long)(ws_size / (2 * sizeof(double)));
    long long nb = NBLOCKS;
    if (nb > maxb) nb = maxb;
    if (nb < 1) nb = 1;
    int nblocks = (int)nb;

    double* partS = (double*)d_ws;
    double* partQ = partS + nblocks;

    fancy_mlp_main<<<nblocks, TPB, 0, stream>>>(x, W, b, R, partS, partQ, nrows);
    fancy_mlp_finish<<<1, 256, 0, stream>>>(partS, partQ, nblocks, (float*)d_out);
}

// Round 6
// 275.834 us; speedup vs baseline: 1.2414x; 1.2414x over previous
//
#include <hip/hip_runtime.h>
#include <hip/hip_bf16.h>
#include <math.h>

#define D 20
#define NROWS 4
#define TPB 256
#define NBLOCKS 1024   // 4 blocks/CU resident if VGPR<=128 -> 16 waves/CU

// Fused per-row pipeline, constants LDS-resident (filled once per block):
//   h2 = relu(x @ M + c)   with M = W^T R (DxD), c = 1 + b @ R
//   h3 = h2 @ W^T + b
//   accumulate S += sum(h3), Q += sum(h3^2)
// R3 lesson: LICM hoists loop-invariant LDS loads into ~440 VGPRs -> spill;
//   defeated with opaque per-iteration zero offset (asm "+v").
// R5 lesson: __launch_bounds__ min-waves arg over-caps (gave 64 VGPR + spill).
//   Instead: trim live set naturally below 128 (float accs, no tail in main,
//   32-bit offsets) so 4 waves/EU happen without forcing.
template <int NR>
__device__ __forceinline__ void process_rows(const float* __restrict__ xp,
                                             const float* sM, const float* sW,
                                             const float* sC, const float* sB,
                                             float& sacc, float& qacc) {
    float h2[NR][D];
    const float4* C4 = (const float4*)sC;
#pragma unroll
    for (int q = 0; q < D / 4; ++q) {
        float4 c = C4[q];
#pragma unroll
        for (int rr = 0; rr < NR; ++rr) {
            h2[rr][4 * q + 0] = c.x;
            h2[rr][4 * q + 1] = c.y;
            h2[rr][4 * q + 2] = c.z;
            h2[rr][4 * q + 3] = c.w;
        }
    }

    const float4* xp4 = (const float4*)xp;
    const float4* M4 = (const float4*)sM;
#pragma unroll
    for (int q = 0; q < D / 4; ++q) {
        float4 xv[NR];
#pragma unroll
        for (int rr = 0; rr < NR; ++rr) xv[rr] = xp4[rr * (D / 4) + q];
#pragma unroll
        for (int dd = 0; dd < 4; ++dd) {
            const int d = 4 * q + dd;
#pragma unroll
            for (int kq = 0; kq < D / 4; ++kq) {
                float4 m = M4[d * (D / 4) + kq];
#pragma unroll
                for (int rr = 0; rr < NR; ++rr) {
                    float xs = (dd == 0) ? xv[rr].x
                             : (dd == 1) ? xv[rr].y
                             : (dd == 2) ? xv[rr].z
                                         : xv[rr].w;
                    h2[rr][4 * kq + 0] = fmaf(xs, m.x, h2[rr][4 * kq + 0]);
                    h2[rr][4 * kq + 1] = fmaf(xs, m.y, h2[rr][4 * kq + 1]);
                    h2[rr][4 * kq + 2] = fmaf(xs, m.z, h2[rr][4 * kq + 2]);
                    h2[rr][4 * kq + 3] = fmaf(xs, m.w, h2[rr][4 * kq + 3]);
                }
            }
        }
    }

#pragma unroll
    for (int rr = 0; rr < NR; ++rr)
#pragma unroll
        for (int k = 0; k < D; ++k) h2[rr][k] = fmaxf(h2[rr][k], 0.f);

    const float4* W4 = (const float4*)sW;
#pragma unroll
    for (int j = 0; j < D; ++j) {
        float bj = sB[j];
        float h3[NR];
#pragma unroll
        for (int rr = 0; rr < NR; ++rr) h3[rr] = bj;
#pragma unroll
        for (int kq = 0; kq < D / 4; ++kq) {
            float4 w = W4[j * (D / 4) + kq];
#pragma unroll
            for (int rr = 0; rr < NR; ++rr) {
                h3[rr] = fmaf(h2[rr][4 * kq + 0], w.x, h3[rr]);
                h3[rr] = fmaf(h2[rr][4 * kq + 1], w.y, h3[rr]);
                h3[rr] = fmaf(h2[rr][4 * kq + 2], w.z, h3[rr]);
                h3[rr] = fmaf(h2[rr][4 * kq + 3], w.w, h3[rr]);
            }
        }
#pragma unroll
        for (int rr = 0; rr < NR; ++rr) {
            sacc += h3[rr];
            qacc = fmaf(h3[rr], h3[rr], qacc);
        }
    }
}

__global__ void __launch_bounds__(TPB)
fancy_mlp_main(const float* __restrict__ x,
               const float* __restrict__ W,
               const float* __restrict__ bvec,
               const float* __restrict__ R,
               double* __restrict__ partS,
               double* __restrict__ partQ,
               unsigned ngroups) {
    __shared__ __align__(16) float sM[D * D];   // M = W^T R
    __shared__ __align__(16) float sW[D * D];   // W copy
    __shared__ __align__(16) float sC[D];       // c = 1 + b @ R
    __shared__ __align__(16) float sB[D];       // b copy

    // Per-block constant build: identical fp ops in every block -> deterministic.
    for (int t = threadIdx.x; t < 2 * D * D + 2 * D; t += TPB) {
        if (t < D * D) {
            int d = t / D, k = t % D;
            float s = 0.f;
#pragma unroll
            for (int j = 0; j < D; ++j) s = fmaf(W[j * D + d], R[j * D + k], s);
            sM[t] = s;
        } else if (t < D * D + D) {
            int k = t - D * D;
            float s = 1.f;
#pragma unroll
            for (int j = 0; j < D; ++j) s = fmaf(bvec[j], R[j * D + k], s);
            sC[k] = s;
        } else if (t < 2 * D * D + D) {
            int u = t - (D * D + D);
            sW[u] = W[u];
        } else {
            sB[t - (2 * D * D + D)] = bvec[t - (2 * D * D + D)];
        }
    }
    __syncthreads();

    unsigned gtid = blockIdx.x * TPB + threadIdx.x;
    unsigned gstride = gridDim.x * TPB;

    // Per-thread float accumulators (<= ~200 terms each), promoted to double
    // only after the loop (keeps fp64 register pairs out of the hot loop).
    float sacc = 0.f, qacc = 0.f;
#pragma clang loop unroll(disable)
    for (unsigned g = gtid; g < ngroups; g += gstride) {
        // Opaque zero re-materialized every iteration: keeps the 440 LDS
        // constants loop-variant so LICM can't hoist them into VGPRs (R3 spill).
        int zoff = 0;
        asm volatile("" : "+v"(zoff));
        process_rows<NROWS>(x + g * (unsigned)(NROWS * D),
                            sM + zoff, sW + zoff, sC + zoff, sB + zoff,
                            sacc, qacc);
    }

    double sd = (double)sacc, qd = (double)qacc;
    // wave(64) shuffle reduce, then per-block partial
#pragma unroll
    for (int off = 32; off > 0; off >>= 1) {
        sd += __shfl_down(sd, off);
        qd += __shfl_down(qd, off);
    }
    __shared__ double rS[TPB / 64], rQ[TPB / 64];
    int lane = threadIdx.x & 63;
    int wid = threadIdx.x >> 6;
    if (lane == 0) { rS[wid] = sd; rQ[wid] = qd; }
    __syncthreads();
    if (threadIdx.x == 0) {
        double S = 0.0, Q = 0.0;
#pragma unroll
        for (int w = 0; w < TPB / 64; ++w) { S += rS[w]; Q += rQ[w]; }
        partS[blockIdx.x] = S;
        partQ[blockIdx.x] = Q;
    }
}

__global__ void __launch_bounds__(256)
fancy_mlp_finish(const double* __restrict__ partS,
                 const double* __restrict__ partQ,
                 int nb,
                 const float* __restrict__ x,
                 const float* __restrict__ W,
                 const float* __restrict__ bvec,
                 const float* __restrict__ R,
                 long long rows_main, long long nrows,
                 float* __restrict__ out) {
    double s = 0.0, q = 0.0;
    for (int i = threadIdx.x; i < nb; i += 256) { s += partS[i]; q += partQ[i]; }
#pragma unroll
    for (int off = 32; off > 0; off >>= 1) {
        s += __shfl_down(s, off);
        q += __shfl_down(q, off);
    }
    __shared__ double rS[4], rQ[4];
    int lane = threadIdx.x & 63;
    int wid = threadIdx.x >> 6;
    if (lane == 0) { rS[wid] = s; rQ[wid] = q; }
    __syncthreads();
    if (threadIdx.x == 0) {
        double S = rS[0] + rS[1] + rS[2] + rS[3];
        double Q = rQ[0] + rQ[1] + rQ[2] + rQ[3];
        // Tail rows not covered by the NROWS-grouped main kernel (0 for B=2M).
        for (long long r = rows_main; r < nrows; ++r) {
            const float* xr = x + r * D;
            float h1[D], h2[D];
            for (int j = 0; j < D; ++j) {
                float t = bvec[j];
                for (int k = 0; k < D; ++k) t = fmaf(xr[k], W[j * D + k], t);
                h1[j] = t;
            }
            for (int k = 0; k < D; ++k) {
                float t = 1.f;
                for (int j = 0; j < D; ++j) t = fmaf(h1[j], R[j * D + k], t);
                h2[k] = fmaxf(t, 0.f);
            }
            for (int j = 0; j < D; ++j) {
                float t = bvec[j];
                for (int k = 0; k < D; ++k) t = fmaf(h2[k], W[j * D + k], t);
                S += (double)t;
                Q += (double)t * (double)t;
            }
        }
        float n = (float)sqrt(Q);
        // torch: while norm > 1: x /= 2  (halving exact in fp32)
        int k = 0;
        float nn = n;
        while (nn > 1.0f) { nn *= 0.5f; ++k; }
        float mult = (nn < 0.8f) ? 10.0f : 1.0f;
        double scale = ldexp(1.0, -k);
        out[0] = (float)(S * scale * (double)mult);
    }
}

extern "C" void kernel_launch(void* const* d_in, const int* in_sizes, int n_in,
                              void* d_out, int out_size, void* d_ws, size_t ws_size,
                              hipStream_t stream) {
    const float* x = (const float*)d_in[0];
    const float* W = (const float*)d_in[1];
    const float* b = (const float*)d_in[2];
    const float* R = (const float*)d_in[3];

    long long nrows = (long long)in_sizes[0] / D;      // 2,000,000
    long long ngroups = nrows / NROWS;                 // 500,000 (exact)
    long long rows_main = ngroups * NROWS;

    long long maxb = (long long)(ws_size / (2 * sizeof(double)));
    long long nb = NBLOCKS;
    if (nb > maxb) nb = maxb;
    if (nb < 1) nb = 1;
    int nblocks = (int)nb;

    double* partS = (double*)d_ws;
    double* partQ = partS + nblocks;

    fancy_mlp_main<<<nblocks, TPB, 0, stream>>>(x, W, b, R, partS, partQ,
                                                (unsigned)ngroups);
    fancy_mlp_finish<<<1, 256, 0, stream>>>(partS, partQ, nblocks,
                                            x, W, b, R, rows_main, nrows,
                                            (float*)d_out);
}

// Round 7
// 229.704 us; speedup vs baseline: 1.4907x; 1.2008x over previous
//
#include <hip/hip_runtime.h>
#include <hip/hip_bf16.h>
#include <hip/hip_fp16.h>
#include <math.h>

#define D 20
#define TPB 256
#define NBLK 1024
#define H2S 40           // ushorts per h2 row (80 B): 20 used + pad; 80B stride -> 2-way-free b128 reads

typedef __attribute__((ext_vector_type(8))) _Float16 half8;
typedef __attribute__((ext_vector_type(4))) float f32x4;

union FragAB {
    half8 v;
    _Float16 h[8];
    ushort u[8];
    uint w[4];
};

__device__ __forceinline__ ushort f2h_bits(float f) {
    union { _Float16 h; ushort u; } cv;
    cv.h = (_Float16)f;   // v_cvt_f16_f32, RNE
    return cv.u;
}

// MFMA reformulation. Per 16-row tile (one wave, no barriers):
//   phase1: D1 = x_tile[16x32pad] @ M[32pad x 20] + c   (2x mfma 16x16x32_f16, N split 16|4)
//   h2 = relu(D1)  -> f16 -> per-wave LDS roundtrip (C-layout -> A-layout, m120 transform)
//   phase2: h3 = h2[16x32pad] @ W^T[32pad x 20] + b     (2x mfma, bias pre-loaded in C)
//   S += sum(h3), Q += sum(h3^2) per lane (valid cols only; invalid cols exact 0 by construction)
// Constants live in 4 B-fragments = 16 VGPRs/lane (loop-invariant registers; the R3-R6
// constant-delivery pathology is gone structurally).
__global__ void __launch_bounds__(TPB)
fancy_mlp_main(const float* __restrict__ x,
               const float* __restrict__ W,
               const float* __restrict__ bvec,
               const float* __restrict__ R,
               double* __restrict__ partS,
               double* __restrict__ partQ,
               unsigned ntiles) {
    __shared__ __align__(16) float sM[D * D];     // M = W^T R
    __shared__ __align__(16) float sW[D * D];     // W copy
    __shared__ __align__(16) float sC[D];         // c = 1 + b @ R
    __shared__ __align__(16) float sB[D];         // b copy
    __shared__ __align__(16) ushort sH2[TPB / 64][16 * H2S];  // per-wave h2 tile

    // Per-block constant build (identical fp ops every block -> deterministic).
    for (int t = threadIdx.x; t < 2 * D * D + 2 * D; t += TPB) {
        if (t < D * D) {
            int d = t / D, k = t % D;
            float s = 0.f;
#pragma unroll
            for (int j = 0; j < D; ++j) s = fmaf(W[j * D + d], R[j * D + k], s);
            sM[t] = s;
        } else if (t < D * D + D) {
            int k = t - D * D;
            float s = 1.f;
#pragma unroll
            for (int j = 0; j < D; ++j) s = fmaf(bvec[j], R[j * D + k], s);
            sC[k] = s;
        } else if (t < 2 * D * D + D) {
            int u = t - (D * D + D);
            sW[u] = W[u];
        } else {
            sB[t - (2 * D * D + D)] = bvec[t - (2 * D * D + D)];
        }
    }
    __syncthreads();

    const int lane = threadIdx.x & 63;
    const int wv = threadIdx.x >> 6;
    const int col = lane & 15;      // n (B/C col) == m (A row)
    const int quad = lane >> 4;
    const int k0 = quad * 8;        // A/B k-offset for this lane

    // ---- Build the 4 constant B-fragments + scalar constants (once) ----
    // B layout (16x16x32): lane holds B[k = quad*8+j][n = lane&15], j=0..7.
    FragAB B1a, B1b, B2a, B2b;
#pragma unroll
    for (int j = 0; j < 8; ++j) {
        int k = k0 + j;
        bool kv = (k < D);
        B1a.u[j] = kv ? f2h_bits(sM[k * D + col]) : (ushort)0;
        B1b.u[j] = (kv && col < 4) ? f2h_bits(sM[k * D + 16 + col]) : (ushort)0;
        B2a.u[j] = kv ? f2h_bits(sW[col * D + k]) : (ushort)0;
        B2b.u[j] = (kv && col < 4) ? f2h_bits(sW[(16 + col) * D + k]) : (ushort)0;
    }
    const float cA = sC[col];
    const float cB = (col < 4) ? sC[16 + col] : 0.f;
    const float bA = sB[col];
    const float bB = (col < 4) ? sB[16 + col] : 0.f;

    ushort* const h2w = &sH2[wv][0];
    // C-layout write base: (row = quad*4 + reg, col); reg via immediate offset reg*H2S.
    const int wr_base = (quad * 4) * H2S + col;
    // A-layout read: lane m=col reads [m][k0 .. k0+7] = 16 B.
    const uint4* const rd_ptr = (const uint4*)(h2w + col * H2S + k0);

    float S = 0.f, Q = 0.f;

    unsigned wgid = blockIdx.x * (TPB / 64) + wv;
    unsigned wstride = gridDim.x * (TPB / 64);
    for (unsigned t = wgid; t < ntiles; t += wstride) {
        // ---- A1: x rows, fp32 -> f16, A-layout. Exec-masked loads: zero overfetch. ----
        const float* xrow = x + (size_t)t * (16 * D) + (size_t)col * D;
        float4 va = make_float4(0.f, 0.f, 0.f, 0.f);
        float4 vb = va;
        if (quad < 3) va = *(const float4*)(xrow + k0);        // k0, k0+1..3 (quad2 = k16..19)
        if (quad < 2) vb = *(const float4*)(xrow + k0 + 4);    // k0+4..7
        FragAB A1;
        A1.h[0] = (_Float16)va.x; A1.h[1] = (_Float16)va.y;
        A1.h[2] = (_Float16)va.z; A1.h[3] = (_Float16)va.w;
        A1.h[4] = (_Float16)vb.x; A1.h[5] = (_Float16)vb.y;
        A1.h[6] = (_Float16)vb.z; A1.h[7] = (_Float16)vb.w;

        // ---- Phase 1: c pre-loaded into C; invalid cols of tile-b get C=0, B=0 -> exact 0 ----
        f32x4 d1a = {cA, cA, cA, cA};
        f32x4 d1b = {cB, cB, cB, cB};
        d1a = __builtin_amdgcn_mfma_f32_16x16x32_f16(A1.v, B1a.v, d1a, 0, 0, 0);
        d1b = __builtin_amdgcn_mfma_f32_16x16x32_f16(A1.v, B1b.v, d1b, 0, 0, 0);

        // ---- relu -> f16 -> LDS (C-layout). Per-wave buffer; DS ops in-order per wave,
        //      all 16 rows x cols 0..31 covered (pad cols written as exact zeros). ----
#pragma unroll
        for (int r = 0; r < 4; ++r) {
            h2w[wr_base + r * H2S]      = f2h_bits(fmaxf(d1a[r], 0.f));
            h2w[wr_base + r * H2S + 16] = f2h_bits(fmaxf(d1b[r], 0.f));
        }

        // ---- A2: read back in A-layout (one b128 per lane, 80B stride -> conflict-free) ----
        FragAB A2;
        uint4 rv = *rd_ptr;
        A2.w[0] = rv.x; A2.w[1] = rv.y; A2.w[2] = rv.z; A2.w[3] = rv.w;

        // ---- Phase 2: bias pre-loaded into C ----
        f32x4 d2a = {bA, bA, bA, bA};
        f32x4 d2b = {bB, bB, bB, bB};
        d2a = __builtin_amdgcn_mfma_f32_16x16x32_f16(A2.v, B2a.v, d2a, 0, 0, 0);
        d2b = __builtin_amdgcn_mfma_f32_16x16x32_f16(A2.v, B2b.v, d2b, 0, 0, 0);

        // ---- Accumulate S, Q (invalid tile-b lanes carry exact 0) ----
#pragma unroll
        for (int r = 0; r < 4; ++r) {
            S += d2a[r] + d2b[r];
            Q = fmaf(d2a[r], d2a[r], Q);
            Q = fmaf(d2b[r], d2b[r], Q);
        }
    }

    // ---- Reduce: wave(64) shuffle in double, then per-block partial ----
    double sd = (double)S, qd = (double)Q;
#pragma unroll
    for (int off = 32; off > 0; off >>= 1) {
        sd += __shfl_down(sd, off);
        qd += __shfl_down(qd, off);
    }
    __shared__ double rS[TPB / 64], rQ[TPB / 64];
    if (lane == 0) { rS[wv] = sd; rQ[wv] = qd; }
    __syncthreads();
    if (threadIdx.x == 0) {
        double Ssum = 0.0, Qsum = 0.0;
#pragma unroll
        for (int w = 0; w < TPB / 64; ++w) { Ssum += rS[w]; Qsum += rQ[w]; }
        partS[blockIdx.x] = Ssum;
        partQ[blockIdx.x] = Qsum;
    }
}

__global__ void __launch_bounds__(256)
fancy_mlp_finish(const double* __restrict__ partS,
                 const double* __restrict__ partQ,
                 int nb,
                 const float* __restrict__ x,
                 const float* __restrict__ W,
                 const float* __restrict__ bvec,
                 const float* __restrict__ R,
                 long long rows_main, long long nrows,
                 float* __restrict__ out) {
    double s = 0.0, q = 0.0;
    for (int i = threadIdx.x; i < nb; i += 256) { s += partS[i]; q += partQ[i]; }
#pragma unroll
    for (int off = 32; off > 0; off >>= 1) {
        s += __shfl_down(s, off);
        q += __shfl_down(q, off);
    }
    __shared__ double rS[4], rQ[4];
    int lane = threadIdx.x & 63;
    int wid = threadIdx.x >> 6;
    if (lane == 0) { rS[wid] = s; rQ[wid] = q; }
    __syncthreads();
    if (threadIdx.x == 0) {
        double S = rS[0] + rS[1] + rS[2] + rS[3];
        double Q = rQ[0] + rQ[1] + rQ[2] + rQ[3];
        // Tail rows not covered by 16-row tiles (0 for B=2M; fp32 path, exactness irrelevant
        // at this count).
        for (long long r = rows_main; r < nrows; ++r) {
            const float* xr = x + r * D;
            float h1[D], h2[D];
            for (int j = 0; j < D; ++j) {
                float t = bvec[j];
                for (int k = 0; k < D; ++k) t = fmaf(xr[k], W[j * D + k], t);
                h1[j] = t;
            }
            for (int k = 0; k < D; ++k) {
                float t = 1.f;
                for (int j = 0; j < D; ++j) t = fmaf(h1[j], R[j * D + k], t);
                h2[k] = fmaxf(t, 0.f);
            }
            for (int j = 0; j < D; ++j) {
                float t = bvec[j];
                for (int k = 0; k < D; ++k) t = fmaf(h2[k], W[j * D + k], t);
                S += (double)t;
                Q += (double)t * (double)t;
            }
        }
        float n = (float)sqrt(Q);
        // torch: while norm > 1: x /= 2  (halving exact in fp32)
        int k = 0;
        float nn = n;
        while (nn > 1.0f) { nn *= 0.5f; ++k; }
        float mult = (nn < 0.8f) ? 10.0f : 1.0f;
        double scale = ldexp(1.0, -k);
        out[0] = (float)(S * scale * (double)mult);
    }
}

extern "C" void kernel_launch(void* const* d_in, const int* in_sizes, int n_in,
                              void* d_out, int out_size, void* d_ws, size_t ws_size,
                              hipStream_t stream) {
    const float* x = (const float*)d_in[0];
    const float* W = (const float*)d_in[1];
    const float* b = (const float*)d_in[2];
    const float* R = (const float*)d_in[3];

    long long nrows = (long long)in_sizes[0] / D;   // 2,000,000
    long long ntiles = nrows / 16;                  // 125,000 (exact)
    long long rows_main = ntiles * 16;

    long long maxb = (long long)(ws_size / (2 * sizeof(double)));
    long long nb = NBLK;
    if (nb > maxb) nb = maxb;
    if (nb < 1) nb = 1;
    int nblocks = (int)nb;

    double* partS = (double*)d_ws;
    double* partQ = partS + nblocks;

    fancy_mlp_main<<<nblocks, TPB, 0, stream>>>(x, W, b, R, partS, partQ,
                                                (unsigned)ntiles);
    fancy_mlp_finish<<<1, 256, 0, stream>>>(partS, partQ, nblocks,
                                            x, W, b, R, rows_main, nrows,
                                            (float*)d_out);
}